// Round 1
// baseline (536.142 us; speedup 1.0000x reference)
//
#include <hip/hip_runtime.h>

#define N_NODES 50000
#define N_EDGES 800000
#define D_HID   128

// ---------------- degree count ----------------
__global__ void deg_count_k(const int* __restrict__ dst, int* __restrict__ cnt, int e) {
    int i = blockIdx.x * 256 + threadIdx.x;
    if (i < e) atomicAdd(&cnt[dst[i]], 1);
}

// ---------------- degree -> dis / dinv ----------------
__global__ void deg_norm_k(const int* __restrict__ cnt, float* __restrict__ dis,
                           float* __restrict__ dinv, int n) {
    int i = blockIdx.x * 256 + threadIdx.x;
    if (i < n) {
        float d = (float)cnt[i] + 1.0f;
        dis[i]  = rsqrtf(d);
        dinv[i] = 1.0f / d;
    }
}

// ---------------- single-block exclusive scan (n=50000) ----------------
__global__ void scan_k(const int* __restrict__ cnt, int* __restrict__ row_ptr, int n) {
    __shared__ int part[1024];
    int t = threadIdx.x;
    int chunk = (n + 1023) >> 10;
    int begin = t * chunk;
    int end   = begin + chunk; if (end > n) end = n;
    int s = 0;
    for (int i = begin; i < end; ++i) s += cnt[i];
    part[t] = s;
    __syncthreads();
    for (int off = 1; off < 1024; off <<= 1) {
        int v = (t >= off) ? part[t - off] : 0;
        __syncthreads();
        part[t] += v;
        __syncthreads();
    }
    int run = (t == 0) ? 0 : part[t - 1];
    for (int i = begin; i < end; ++i) { row_ptr[i] = run; run += cnt[i]; }
    if (t == 1023) row_ptr[n] = part[1023];
}

// ---------------- scatter edges into CSR ----------------
__global__ void scatter_k(const int* __restrict__ src, const int* __restrict__ dst,
                          const int* __restrict__ row_ptr, int* __restrict__ cursor,
                          int* __restrict__ col, float* __restrict__ ew,
                          const float* __restrict__ dis, int e) {
    int i = blockIdx.x * 256 + threadIdx.x;
    if (i < e) {
        int s = src[i], d = dst[i];
        int pos = row_ptr[d] + atomicAdd(&cursor[d], 1);
        col[pos] = s;
        ew[pos]  = dis[s];
    }
}

// ---------------- tiled fp32 GEMM: C[M x 128] = A[M x K] * B[K x 128] ----------------
#define BM 64
#define BN 128
#define BK 16
#define LDA 68   // padded (multiple of 4 for float4 alignment, breaks bank stride)

__global__ __launch_bounds__(256) void gemm128_k(const float* __restrict__ A,
                                                 const float* __restrict__ B,
                                                 float* __restrict__ C, int M, int K) {
    __shared__ float As[BK * LDA];   // transposed: As[k][m]
    __shared__ float Bs[BK * BN];    // Bs[k][n]
    int tid = threadIdx.x;
    int r0  = blockIdx.x * BM;
    int tc  = tid & 31;   // 32 col groups * 4 cols
    int tr  = tid >> 5;   // 8 row groups * 8 rows

    float acc[8][4];
#pragma unroll
    for (int i = 0; i < 8; ++i)
#pragma unroll
        for (int j = 0; j < 4; ++j) acc[i][j] = 0.f;

    int a_row = tid >> 2;        // 0..63
    int a_k4  = (tid & 3) * 4;   // 0,4,8,12

    for (int k0 = 0; k0 < K; k0 += BK) {
        // stage A tile (64 x 16), transposed into LDS
        float4 av = make_float4(0.f, 0.f, 0.f, 0.f);
        int grow = r0 + a_row;
        if (grow < M) av = *(const float4*)&A[(size_t)grow * K + k0 + a_k4];
        As[(a_k4 + 0) * LDA + a_row] = av.x;
        As[(a_k4 + 1) * LDA + a_row] = av.y;
        As[(a_k4 + 2) * LDA + a_row] = av.z;
        As[(a_k4 + 3) * LDA + a_row] = av.w;
        // stage B tile (16 x 128)
#pragma unroll
        for (int i = 0; i < 2; ++i) {
            int idx = tid + i * 256;        // 0..511 float4 slots
            int bk  = idx >> 5;             // 0..15
            int bc  = (idx & 31) * 4;       // 0..124
            *(float4*)&Bs[bk * BN + bc] = *(const float4*)&B[(size_t)(k0 + bk) * BN + bc];
        }
        __syncthreads();
#pragma unroll
        for (int kk = 0; kk < BK; ++kk) {
            float4 b4 = *(const float4*)&Bs[kk * BN + tc * 4];
            float4 a0 = *(const float4*)&As[kk * LDA + tr * 8];
            float4 a1 = *(const float4*)&As[kk * LDA + tr * 8 + 4];
            float a[8] = {a0.x, a0.y, a0.z, a0.w, a1.x, a1.y, a1.z, a1.w};
            float b[4] = {b4.x, b4.y, b4.z, b4.w};
#pragma unroll
            for (int i = 0; i < 8; ++i)
#pragma unroll
                for (int j = 0; j < 4; ++j) acc[i][j] += a[i] * b[j];
        }
        __syncthreads();
    }
#pragma unroll
    for (int i = 0; i < 8; ++i) {
        int row = r0 + tr * 8 + i;
        if (row < M)
            *(float4*)&C[(size_t)row * BN + tc * 4] =
                make_float4(acc[i][0], acc[i][1], acc[i][2], acc[i][3]);
    }
}

// ---------------- aggregate: out = relu(dis[n]*sum_e(ew*h[src]) + h[n]*dinv[n] + b) ----------------
__global__ __launch_bounds__(256) void aggregate_k(const float* __restrict__ h,
                                                   const int* __restrict__ row_ptr,
                                                   const int* __restrict__ col,
                                                   const float* __restrict__ ew,
                                                   const float* __restrict__ dis,
                                                   const float* __restrict__ dinv,
                                                   const float* __restrict__ bias,
                                                   float* __restrict__ out, int n) {
    int node = blockIdx.x * 4 + (threadIdx.x >> 6);
    if (node >= n) return;
    int lane = threadIdx.x & 63;
    int c0   = lane * 2;

    float ax = 0.f, ay = 0.f;
    int beg = row_ptr[node], end = row_ptr[node + 1];
    for (int e = beg; e < end; ++e) {
        int   s = col[e];
        float w = ew[e];
        float2 hv = *(const float2*)&h[(size_t)s * D_HID + c0];
        ax += w * hv.x;
        ay += w * hv.y;
    }
    float dn = dis[node], di = dinv[node];
    float2 hn = *(const float2*)&h[(size_t)node * D_HID + c0];
    float2 bv = *(const float2*)&bias[c0];
    float ox = fmaxf(ax * dn + hn.x * di + bv.x, 0.f);
    float oy = fmaxf(ay * dn + hn.y * di + bv.y, 0.f);
    *(float2*)&out[(size_t)node * D_HID + c0] = make_float2(ox, oy);
}

extern "C" void kernel_launch(void* const* d_in, const int* in_sizes, int n_in,
                              void* d_out, int out_size, void* d_ws, size_t ws_size,
                              hipStream_t stream) {
    const float* x  = (const float*)d_in[0];
    const int*   ei = (const int*)d_in[1];
    const float* W0 = (const float*)d_in[2];
    const float* b0 = (const float*)d_in[3];
    const float* W1 = (const float*)d_in[4];
    const float* b1 = (const float*)d_in[5];
    const float* W2 = (const float*)d_in[6];
    const float* b2 = (const float*)d_in[7];
    float* out = (float*)d_out;

    const int N = N_NODES, E = N_EDGES;
    const int* src = ei;
    const int* dst = ei + E;

    // workspace carve-up
    char* w = (char*)d_ws;
    size_t off = 0;
    auto alloc = [&](size_t bytes) {
        size_t o = off;
        off += (bytes + 255) & ~(size_t)255;
        return o;
    };
    int*   cnt    = (int*)(w + alloc((size_t)N * 4));
    int*   cursor = (int*)(w + alloc((size_t)N * 4));
    float* dis    = (float*)(w + alloc((size_t)N * 4));
    float* dinv   = (float*)(w + alloc((size_t)N * 4));
    int*   rp     = (int*)(w + alloc((size_t)(N + 1) * 4));
    int*   col    = (int*)(w + alloc((size_t)E * 4));
    float* ewt    = (float*)(w + alloc((size_t)E * 4));
    float* hbuf   = (float*)(w + alloc((size_t)N * D_HID * 4));
    (void)ws_size; (void)n_in; (void)in_sizes; (void)out_size;

    hipMemsetAsync(cnt, 0, (size_t)N * 4, stream);
    hipMemsetAsync(cursor, 0, (size_t)N * 4, stream);

    deg_count_k<<<(E + 255) / 256, 256, 0, stream>>>(dst, cnt, E);
    deg_norm_k<<<(N + 255) / 256, 256, 0, stream>>>(cnt, dis, dinv, N);
    scan_k<<<1, 1024, 0, stream>>>(cnt, rp, N);
    scatter_k<<<(E + 255) / 256, 256, 0, stream>>>(src, dst, rp, cursor, col, ewt, dis, E);

    int gemm_grid = (N + BM - 1) / BM;   // 782

    // layer 0: h = x @ W0 ; out_l0 (-> d_out as scratch) = agg(h) with b0, relu
    gemm128_k<<<gemm_grid, 256, 0, stream>>>(x, W0, hbuf, N, 256);
    aggregate_k<<<N / 4, 256, 0, stream>>>(hbuf, rp, col, ewt, dis, dinv, b0, out, N);

    // layer 1: h = out_l0 @ W1 ; out_l1 (-> d_out) = agg(h) with b1, relu
    gemm128_k<<<gemm_grid, 256, 0, stream>>>(out, W1, hbuf, N, 128);
    aggregate_k<<<N / 4, 256, 0, stream>>>(hbuf, rp, col, ewt, dis, dinv, b1, out, N);

    // layer 2: h = out_l1 @ W2 ; final -> d_out
    gemm128_k<<<gemm_grid, 256, 0, stream>>>(out, W2, hbuf, N, 128);
    aggregate_k<<<N / 4, 256, 0, stream>>>(hbuf, rp, col, ewt, dis, dinv, b2, out, N);
}

// Round 2
// 520.707 us; speedup vs baseline: 1.0296x; 1.0296x over previous
//
#include <hip/hip_runtime.h>

#define N_NODES 50000
#define N_EDGES 800000
#define D_HID   128

typedef unsigned int uint;

// ---------------- degree count ----------------
__global__ void deg_count_k(const int* __restrict__ dst, int* __restrict__ cnt, int e) {
    int i = blockIdx.x * 256 + threadIdx.x;
    if (i < e) atomicAdd(&cnt[dst[i]], 1);
}

// ---------------- degree -> dis / dinv ----------------
__global__ void deg_norm_k(const int* __restrict__ cnt, float* __restrict__ dis,
                           float* __restrict__ dinv, int n) {
    int i = blockIdx.x * 256 + threadIdx.x;
    if (i < n) {
        float d = (float)cnt[i] + 1.0f;
        dis[i]  = rsqrtf(d);
        dinv[i] = 1.0f / d;
    }
}

// ---------------- single-block exclusive scan (n=50000) ----------------
__global__ void scan_k(const int* __restrict__ cnt, int* __restrict__ row_ptr, int n) {
    __shared__ int part[1024];
    int t = threadIdx.x;
    int chunk = (n + 1023) >> 10;
    int begin = t * chunk;
    int end   = begin + chunk; if (end > n) end = n;
    int s = 0;
    for (int i = begin; i < end; ++i) s += cnt[i];
    part[t] = s;
    __syncthreads();
    for (int off = 1; off < 1024; off <<= 1) {
        int v = (t >= off) ? part[t - off] : 0;
        __syncthreads();
        part[t] += v;
        __syncthreads();
    }
    int run = (t == 0) ? 0 : part[t - 1];
    for (int i = begin; i < end; ++i) { row_ptr[i] = run; run += cnt[i]; }
    if (t == 1023) row_ptr[n] = part[1023];
}

// ---------------- scatter edges into CSR ----------------
__global__ void scatter_k(const int* __restrict__ src, const int* __restrict__ dst,
                          const int* __restrict__ row_ptr, int* __restrict__ cursor,
                          int* __restrict__ col, float* __restrict__ ew,
                          const float* __restrict__ dis, int e) {
    int i = blockIdx.x * 256 + threadIdx.x;
    if (i < e) {
        int s = src[i], d = dst[i];
        int pos = row_ptr[d] + atomicAdd(&cursor[d], 1);
        col[pos] = s;
        ew[pos]  = dis[s];
    }
}

// ---- fp32 -> bf16 (RTNE) ----
__device__ inline unsigned short f2bf(float f) {
    unsigned u = __float_as_uint(f);
    unsigned rounding = 0x7fffu + ((u >> 16) & 1u);
    return (unsigned short)((u + rounding) >> 16);
}

// ---------------- tiled fp32 GEMM: Hb[M x 128](bf16) = A[M x K] * B[K x 128] ----------------
#define BM 64
#define BN 128
#define BK 16
#define LDA 68   // padded

__global__ __launch_bounds__(256) void gemm128_k(const float* __restrict__ A,
                                                 const float* __restrict__ B,
                                                 unsigned short* __restrict__ Hb,
                                                 int M, int K) {
    __shared__ float As[BK * LDA];   // transposed: As[k][m]
    __shared__ float Bs[BK * BN];    // Bs[k][n]
    int tid = threadIdx.x;
    int r0  = blockIdx.x * BM;
    int tc  = tid & 31;   // 32 col groups * 4 cols
    int tr  = tid >> 5;   // 8 row groups * 8 rows

    float acc[8][4];
#pragma unroll
    for (int i = 0; i < 8; ++i)
#pragma unroll
        for (int j = 0; j < 4; ++j) acc[i][j] = 0.f;

    int a_row = tid >> 2;        // 0..63
    int a_k4  = (tid & 3) * 4;   // 0,4,8,12

    for (int k0 = 0; k0 < K; k0 += BK) {
        float4 av = make_float4(0.f, 0.f, 0.f, 0.f);
        int grow = r0 + a_row;
        if (grow < M) av = *(const float4*)&A[(size_t)grow * K + k0 + a_k4];
        As[(a_k4 + 0) * LDA + a_row] = av.x;
        As[(a_k4 + 1) * LDA + a_row] = av.y;
        As[(a_k4 + 2) * LDA + a_row] = av.z;
        As[(a_k4 + 3) * LDA + a_row] = av.w;
#pragma unroll
        for (int i = 0; i < 2; ++i) {
            int idx = tid + i * 256;
            int bk  = idx >> 5;
            int bc  = (idx & 31) * 4;
            *(float4*)&Bs[bk * BN + bc] = *(const float4*)&B[(size_t)(k0 + bk) * BN + bc];
        }
        __syncthreads();
#pragma unroll
        for (int kk = 0; kk < BK; ++kk) {
            float4 b4 = *(const float4*)&Bs[kk * BN + tc * 4];
            float4 a0 = *(const float4*)&As[kk * LDA + tr * 8];
            float4 a1 = *(const float4*)&As[kk * LDA + tr * 8 + 4];
            float a[8] = {a0.x, a0.y, a0.z, a0.w, a1.x, a1.y, a1.z, a1.w};
            float b[4] = {b4.x, b4.y, b4.z, b4.w};
#pragma unroll
            for (int i = 0; i < 8; ++i)
#pragma unroll
                for (int j = 0; j < 4; ++j) acc[i][j] += a[i] * b[j];
        }
        __syncthreads();
    }
#pragma unroll
    for (int i = 0; i < 8; ++i) {
        int row = r0 + tr * 8 + i;
        if (row < M) {
            uint lo = (uint)f2bf(acc[i][0]) | ((uint)f2bf(acc[i][1]) << 16);
            uint hi = (uint)f2bf(acc[i][2]) | ((uint)f2bf(acc[i][3]) << 16);
            uint2 p = make_uint2(lo, hi);
            *(uint2*)&Hb[(size_t)row * BN + tc * 4] = p;
        }
    }
}

// ---------------- aggregate: out = relu(dis[n]*sum_e(ew*hb[src]) + hb[n]*dinv[n] + b) ----------------
__global__ __launch_bounds__(256) void aggregate_k(const unsigned short* __restrict__ hb,
                                                   const int* __restrict__ row_ptr,
                                                   const int* __restrict__ col,
                                                   const float* __restrict__ ew,
                                                   const float* __restrict__ dis,
                                                   const float* __restrict__ dinv,
                                                   const float* __restrict__ bias,
                                                   float* __restrict__ out, int n) {
    int node = blockIdx.x * 4 + (threadIdx.x >> 6);
    if (node >= n) return;
    int lane = threadIdx.x & 63;
    // each lane owns columns c0, c0+1 -> one packed uint per row
    const char* base = (const char*)hb + (lane << 2);   // lane*4 bytes

    float ax = 0.f, ay = 0.f;
    int beg = row_ptr[node], end = row_ptr[node + 1];
    for (int e = beg; e < end; ++e) {
        int   s = col[e];
        float w = ew[e];
        uint  u = *(const uint*)(base + ((size_t)s << 8));   // row stride 256B
        ax += w * __uint_as_float(u << 16);
        ay += w * __uint_as_float(u & 0xffff0000u);
    }
    float dn = dis[node], di = dinv[node];
    uint un = *(const uint*)(base + ((size_t)node << 8));
    float hx = __uint_as_float(un << 16);
    float hy = __uint_as_float(un & 0xffff0000u);
    int c0 = lane * 2;
    float2 bv = *(const float2*)&bias[c0];
    float ox = fmaxf(ax * dn + hx * di + bv.x, 0.f);
    float oy = fmaxf(ay * dn + hy * di + bv.y, 0.f);
    *(float2*)&out[(size_t)node * D_HID + c0] = make_float2(ox, oy);
}

extern "C" void kernel_launch(void* const* d_in, const int* in_sizes, int n_in,
                              void* d_out, int out_size, void* d_ws, size_t ws_size,
                              hipStream_t stream) {
    const float* x  = (const float*)d_in[0];
    const int*   ei = (const int*)d_in[1];
    const float* W0 = (const float*)d_in[2];
    const float* b0 = (const float*)d_in[3];
    const float* W1 = (const float*)d_in[4];
    const float* b1 = (const float*)d_in[5];
    const float* W2 = (const float*)d_in[6];
    const float* b2 = (const float*)d_in[7];
    float* out = (float*)d_out;

    const int N = N_NODES, E = N_EDGES;
    const int* src = ei;
    const int* dst = ei + E;

    char* w = (char*)d_ws;
    size_t off = 0;
    auto alloc = [&](size_t bytes) {
        size_t o = off;
        off += (bytes + 255) & ~(size_t)255;
        return o;
    };
    int*            cnt    = (int*)(w + alloc((size_t)N * 4));
    int*            cursor = (int*)(w + alloc((size_t)N * 4));
    float*          dis    = (float*)(w + alloc((size_t)N * 4));
    float*          dinv   = (float*)(w + alloc((size_t)N * 4));
    int*            rp     = (int*)(w + alloc((size_t)(N + 1) * 4));
    int*            col    = (int*)(w + alloc((size_t)E * 4));
    float*          ewt    = (float*)(w + alloc((size_t)E * 4));
    unsigned short* hb     = (unsigned short*)(w + alloc((size_t)N * D_HID * 2));
    (void)ws_size; (void)n_in; (void)in_sizes; (void)out_size;

    hipMemsetAsync(cnt, 0, (size_t)N * 4, stream);
    hipMemsetAsync(cursor, 0, (size_t)N * 4, stream);

    deg_count_k<<<(E + 255) / 256, 256, 0, stream>>>(dst, cnt, E);
    deg_norm_k<<<(N + 255) / 256, 256, 0, stream>>>(cnt, dis, dinv, N);
    scan_k<<<1, 1024, 0, stream>>>(cnt, rp, N);
    scatter_k<<<(E + 255) / 256, 256, 0, stream>>>(src, dst, rp, cursor, col, ewt, dis, E);

    int gemm_grid = (N + BM - 1) / BM;

    gemm128_k<<<gemm_grid, 256, 0, stream>>>(x, W0, hb, N, 256);
    aggregate_k<<<N / 4, 256, 0, stream>>>(hb, rp, col, ewt, dis, dinv, b0, out, N);

    gemm128_k<<<gemm_grid, 256, 0, stream>>>(out, W1, hb, N, 128);
    aggregate_k<<<N / 4, 256, 0, stream>>>(hb, rp, col, ewt, dis, dinv, b1, out, N);

    gemm128_k<<<gemm_grid, 256, 0, stream>>>(out, W2, hb, N, 128);
    aggregate_k<<<N / 4, 256, 0, stream>>>(hb, rp, col, ewt, dis, dinv, b2, out, N);
}

// Round 3
// 361.556 us; speedup vs baseline: 1.4829x; 1.4402x over previous
//
#include <hip/hip_runtime.h>

#define N_NODES 50000
#define N_EDGES 800000
#define D_HID   128

typedef unsigned int uint;
typedef unsigned short ushort;
typedef __attribute__((ext_vector_type(8))) short short8;
typedef __attribute__((ext_vector_type(4))) float f32x4;

// ---------------- degree count ----------------
__global__ void deg_count_k(const int* __restrict__ dst, int* __restrict__ cnt, int e) {
    int i = blockIdx.x * 256 + threadIdx.x;
    if (i < e) atomicAdd(&cnt[dst[i]], 1);
}

// ---------------- degree -> dis / dinv ----------------
__global__ void deg_norm_k(const int* __restrict__ cnt, float* __restrict__ dis,
                           float* __restrict__ dinv, int n) {
    int i = blockIdx.x * 256 + threadIdx.x;
    if (i < n) {
        float d = (float)cnt[i] + 1.0f;
        dis[i]  = rsqrtf(d);
        dinv[i] = 1.0f / d;
    }
}

// ---------------- single-block exclusive scan (n=50000) ----------------
__global__ void scan_k(const int* __restrict__ cnt, int* __restrict__ row_ptr, int n) {
    __shared__ int part[1024];
    int t = threadIdx.x;
    int chunk = (n + 1023) >> 10;
    int begin = t * chunk;
    int end   = begin + chunk; if (end > n) end = n;
    int s = 0;
    for (int i = begin; i < end; ++i) s += cnt[i];
    part[t] = s;
    __syncthreads();
    for (int off = 1; off < 1024; off <<= 1) {
        int v = (t >= off) ? part[t - off] : 0;
        __syncthreads();
        part[t] += v;
        __syncthreads();
    }
    int run = (t == 0) ? 0 : part[t - 1];
    for (int i = begin; i < end; ++i) { row_ptr[i] = run; run += cnt[i]; }
    if (t == 1023) row_ptr[n] = part[1023];
}

// ---------------- scatter edges into CSR ----------------
__global__ void scatter_k(const int* __restrict__ src, const int* __restrict__ dst,
                          const int* __restrict__ row_ptr, int* __restrict__ cursor,
                          int* __restrict__ col, float* __restrict__ ew,
                          const float* __restrict__ dis, int e) {
    int i = blockIdx.x * 256 + threadIdx.x;
    if (i < e) {
        int s = src[i], d = dst[i];
        int pos = row_ptr[d] + atomicAdd(&cursor[d], 1);
        col[pos] = s;
        ew[pos]  = dis[s];
    }
}

// ---- fp32 -> bf16 (RTNE) ----
__device__ inline ushort f2bf(float f) {
    unsigned u = __float_as_uint(f);
    unsigned rounding = 0x7fffu + ((u >> 16) & 1u);
    return (ushort)((u + rounding) >> 16);
}

// ---------------- W[K][128] fp32 -> Wt[128][K] bf16 ----------------
__global__ void wtrans_k(const float* __restrict__ W, ushort* __restrict__ Wt, int K) {
    int i = blockIdx.x * 256 + threadIdx.x;
    if (i < K * 128) {
        int k = i >> 7, n = i & 127;
        Wt[(size_t)n * K + k] = f2bf(W[i]);
    }
}

// ---------------- MFMA GEMM: H[M x 128](bf16) = A[M x K] * Wt^T ----------------
// no LDS: A-frags and B-frags loaded directly from global (Wt is L1/L2-hot).
// mfma_f32_16x16x32_bf16: A row = lane&15, k = (lane>>4)*8 + j
//                         B col = lane&15, k = (lane>>4)*8 + j
//                         D col = lane&15, row = (lane>>4)*4 + j   [m89 verified]
template<int K, bool AF32>
__global__ __launch_bounds__(256) void mfma_gemm_k(const void* __restrict__ Ap,
                                                   const ushort* __restrict__ Bt, // [128][K] bf16
                                                   ushort* __restrict__ H,        // [M][128] bf16
                                                   int M) {
    int tid = threadIdx.x;
    int w   = tid >> 6;
    int l   = tid & 63;
    int row = blockIdx.x * 64 + w * 16 + (l & 15);
    int rc  = row < M ? row : M - 1;
    int kg  = (l >> 4) * 8;

    const ushort* A16 = (const ushort*)Ap;
    const float*  A32 = (const float*)Ap;

    f32x4 acc[8];
#pragma unroll
    for (int c = 0; c < 8; ++c) acc[c] = (f32x4){0.f, 0.f, 0.f, 0.f};

#pragma unroll
    for (int k0 = 0; k0 < K; k0 += 32) {
        short8 a;
        if (AF32) {
            const float* ap = &A32[(size_t)rc * K + k0 + kg];
            float4 f0 = *(const float4*)ap;
            float4 f1 = *(const float4*)(ap + 4);
            a[0] = (short)f2bf(f0.x); a[1] = (short)f2bf(f0.y);
            a[2] = (short)f2bf(f0.z); a[3] = (short)f2bf(f0.w);
            a[4] = (short)f2bf(f1.x); a[5] = (short)f2bf(f1.y);
            a[6] = (short)f2bf(f1.z); a[7] = (short)f2bf(f1.w);
        } else {
            a = *(const short8*)&A16[(size_t)rc * K + k0 + kg];
        }
#pragma unroll
        for (int c = 0; c < 8; ++c) {
            short8 b = *(const short8*)&Bt[(size_t)(c * 16 + (l & 15)) * K + k0 + kg];
            acc[c] = __builtin_amdgcn_mfma_f32_16x16x32_bf16(a, b, acc[c], 0, 0, 0);
        }
    }

    int r_base = blockIdx.x * 64 + w * 16 + (l >> 4) * 4;
    int colb   = l & 15;
#pragma unroll
    for (int c = 0; c < 8; ++c) {
#pragma unroll
        for (int j = 0; j < 4; ++j) {
            int r = r_base + j;
            if (r < M) H[(size_t)r * 128 + c * 16 + colb] = f2bf(acc[c][j]);
        }
    }
}

// ---------------- aggregate: relu(dis[n]*sum_e(ew*hb[src]) + hb[n]*dinv[n] + b) ----------------
// 8-wide edge batching for memory-level parallelism (latency-bound otherwise).
template<bool LAST>
__global__ __launch_bounds__(256) void aggregate_k(const ushort* __restrict__ hb,
                                                   const int* __restrict__ row_ptr,
                                                   const int* __restrict__ col,
                                                   const float* __restrict__ ew,
                                                   const float* __restrict__ dis,
                                                   const float* __restrict__ dinv,
                                                   const float* __restrict__ bias,
                                                   ushort* __restrict__ act,
                                                   float* __restrict__ out, int n) {
    int node = blockIdx.x * 4 + (threadIdx.x >> 6);
    if (node >= n) return;
    int lane = threadIdx.x & 63;
    const char* base = (const char*)hb + (lane << 2);   // lane*4 bytes, row stride 256B

    float ax = 0.f, ay = 0.f;
    int beg = row_ptr[node], end = row_ptr[node + 1];
    for (int e = beg; e < end; e += 8) {
        int   s[8]; float wv[8];
#pragma unroll
        for (int q = 0; q < 8; ++q) {
            int idx = e + q;
            bool v  = idx < end;
            int ic  = v ? idx : (end - 1);
            s[q]  = col[ic];
            wv[q] = v ? ew[ic] : 0.f;
        }
        uint u[8];
#pragma unroll
        for (int q = 0; q < 8; ++q)
            u[q] = *(const uint*)(base + ((size_t)s[q] << 8));
#pragma unroll
        for (int q = 0; q < 8; ++q) {
            ax += wv[q] * __uint_as_float(u[q] << 16);
            ay += wv[q] * __uint_as_float(u[q] & 0xffff0000u);
        }
    }
    float dn = dis[node], di = dinv[node];
    uint un = *(const uint*)(base + ((size_t)node << 8));
    float hx = __uint_as_float(un << 16);
    float hy = __uint_as_float(un & 0xffff0000u);
    int c0 = lane * 2;
    float2 bv = *(const float2*)&bias[c0];
    float ox = fmaxf(ax * dn + hx * di + bv.x, 0.f);
    float oy = fmaxf(ay * dn + hy * di + bv.y, 0.f);
    if (LAST) {
        *(float2*)&out[(size_t)node * D_HID + c0] = make_float2(ox, oy);
    } else {
        uint p = (uint)f2bf(ox) | ((uint)f2bf(oy) << 16);
        *(uint*)((char*)act + ((size_t)node << 8) + (lane << 2)) = p;
    }
}

extern "C" void kernel_launch(void* const* d_in, const int* in_sizes, int n_in,
                              void* d_out, int out_size, void* d_ws, size_t ws_size,
                              hipStream_t stream) {
    const float* x  = (const float*)d_in[0];
    const int*   ei = (const int*)d_in[1];
    const float* W0 = (const float*)d_in[2];
    const float* b0 = (const float*)d_in[3];
    const float* W1 = (const float*)d_in[4];
    const float* b1 = (const float*)d_in[5];
    const float* W2 = (const float*)d_in[6];
    const float* b2 = (const float*)d_in[7];
    float* out = (float*)d_out;

    const int N = N_NODES, E = N_EDGES;
    const int* src = ei;
    const int* dst = ei + E;

    char* w = (char*)d_ws;
    size_t off = 0;
    auto alloc = [&](size_t bytes) {
        size_t o = off;
        off += (bytes + 255) & ~(size_t)255;
        return o;
    };
    int*    cnt    = (int*)(w + alloc((size_t)N * 4));
    int*    cursor = (int*)(w + alloc((size_t)N * 4));
    float*  dis    = (float*)(w + alloc((size_t)N * 4));
    float*  dinv   = (float*)(w + alloc((size_t)N * 4));
    int*    rp     = (int*)(w + alloc((size_t)(N + 1) * 4));
    int*    col    = (int*)(w + alloc((size_t)E * 4));
    float*  ewt    = (float*)(w + alloc((size_t)E * 4));
    ushort* hb     = (ushort*)(w + alloc((size_t)N * D_HID * 2));
    ushort* act    = (ushort*)(w + alloc((size_t)N * D_HID * 2));
    ushort* Wt0    = (ushort*)(w + alloc((size_t)128 * 256 * 2));
    ushort* Wt1    = (ushort*)(w + alloc((size_t)128 * 128 * 2));
    ushort* Wt2    = (ushort*)(w + alloc((size_t)128 * 128 * 2));
    (void)ws_size; (void)n_in; (void)in_sizes; (void)out_size;

    hipMemsetAsync(cnt, 0, (size_t)N * 4, stream);
    hipMemsetAsync(cursor, 0, (size_t)N * 4, stream);

    deg_count_k<<<(E + 255) / 256, 256, 0, stream>>>(dst, cnt, E);
    deg_norm_k<<<(N + 255) / 256, 256, 0, stream>>>(cnt, dis, dinv, N);
    scan_k<<<1, 1024, 0, stream>>>(cnt, rp, N);
    scatter_k<<<(E + 255) / 256, 256, 0, stream>>>(src, dst, rp, cursor, col, ewt, dis, E);

    wtrans_k<<<(256 * 128 + 255) / 256, 256, 0, stream>>>(W0, Wt0, 256);
    wtrans_k<<<(128 * 128 + 255) / 256, 256, 0, stream>>>(W1, Wt1, 128);
    wtrans_k<<<(128 * 128 + 255) / 256, 256, 0, stream>>>(W2, Wt2, 128);

    int gemm_grid = (N + 63) / 64;
    int agg_grid  = (N + 3) / 4;

    // layer 0
    mfma_gemm_k<256, true><<<gemm_grid, 256, 0, stream>>>(x, Wt0, hb, N);
    aggregate_k<false><<<agg_grid, 256, 0, stream>>>(hb, rp, col, ewt, dis, dinv, b0, act, out, N);
    // layer 1
    mfma_gemm_k<128, false><<<gemm_grid, 256, 0, stream>>>(act, Wt1, hb, N);
    aggregate_k<false><<<agg_grid, 256, 0, stream>>>(hb, rp, col, ewt, dis, dinv, b1, act, out, N);
    // layer 2
    mfma_gemm_k<128, false><<<gemm_grid, 256, 0, stream>>>(act, Wt2, hb, N);
    aggregate_k<true><<<agg_grid, 256, 0, stream>>>(hb, rp, col, ewt, dis, dinv, b2, act, out, N);
}

// Round 4
// 295.316 us; speedup vs baseline: 1.8155x; 1.2243x over previous
//
#include <hip/hip_runtime.h>

#define N_NODES 50000
#define N_EDGES 800000
#define D_HID   128

typedef unsigned int uint;
typedef unsigned short ushort;
typedef __attribute__((ext_vector_type(8))) short short8;
typedef __attribute__((ext_vector_type(4))) float f32x4;

#define SCAN_NB ((N_NODES + 255) / 256)   // 196

// ---------------- degree count ----------------
__global__ void deg_count_k(const int* __restrict__ dst, int* __restrict__ cnt, int e) {
    int i = blockIdx.x * 256 + threadIdx.x;
    if (i < e) atomicAdd(&cnt[dst[i]], 1);
}

// ---------------- degree -> dis / dinv ----------------
__global__ void deg_norm_k(const int* __restrict__ cnt, float* __restrict__ dis,
                           float* __restrict__ dinv, int n) {
    int i = blockIdx.x * 256 + threadIdx.x;
    if (i < n) {
        float d = (float)cnt[i] + 1.0f;
        dis[i]  = rsqrtf(d);
        dinv[i] = 1.0f / d;
    }
}

// ---------------- 3-phase multi-block exclusive scan ----------------
__global__ void bsum_k(const int* __restrict__ cnt, int* __restrict__ bsum, int n) {
    int i = blockIdx.x * 256 + threadIdx.x;
    int v = (i < n) ? cnt[i] : 0;
#pragma unroll
    for (int off = 32; off; off >>= 1) v += __shfl_down(v, off, 64);
    __shared__ int ws[4];
    int lane = threadIdx.x & 63, w = threadIdx.x >> 6;
    if (lane == 0) ws[w] = v;
    __syncthreads();
    if (threadIdx.x == 0) bsum[blockIdx.x] = ws[0] + ws[1] + ws[2] + ws[3];
}

__global__ void bscan_k(const int* __restrict__ bsum, int* __restrict__ boff,
                        int* __restrict__ row_ptr_end, int nb) {
    __shared__ int s[256];
    int t = threadIdx.x;
    int v = (t < nb) ? bsum[t] : 0;
    s[t] = v;
    __syncthreads();
    for (int off = 1; off < 256; off <<= 1) {
        int u = (t >= off) ? s[t - off] : 0;
        __syncthreads();
        s[t] += u;
        __syncthreads();
    }
    if (t < nb) boff[t] = s[t] - v;        // exclusive
    if (t == 255) *row_ptr_end = s[255];   // total -> row_ptr[n]
}

__global__ void scan3_k(const int* __restrict__ cnt, const int* __restrict__ boff,
                        int* __restrict__ row_ptr, int n) {
    __shared__ int s[256];
    int i = blockIdx.x * 256 + threadIdx.x;
    int t = threadIdx.x;
    int v = (i < n) ? cnt[i] : 0;
    s[t] = v;
    __syncthreads();
    for (int off = 1; off < 256; off <<= 1) {
        int u = (t >= off) ? s[t - off] : 0;
        __syncthreads();
        s[t] += u;
        __syncthreads();
    }
    if (i < n) row_ptr[i] = boff[blockIdx.x] + s[t] - v;
}

// ---------------- scatter edges into CSR ----------------
__global__ void scatter_k(const int* __restrict__ src, const int* __restrict__ dst,
                          const int* __restrict__ row_ptr, int* __restrict__ cursor,
                          int* __restrict__ col, float* __restrict__ ew,
                          const float* __restrict__ dis, int e) {
    int i = blockIdx.x * 256 + threadIdx.x;
    if (i < e) {
        int s = src[i], d = dst[i];
        int pos = row_ptr[d] + atomicAdd(&cursor[d], 1);
        col[pos] = s;
        ew[pos]  = dis[s];
    }
}

// ---- fp32 -> bf16 (RTNE) ----
__device__ inline ushort f2bf(float f) {
    unsigned u = __float_as_uint(f);
    unsigned rounding = 0x7fffu + ((u >> 16) & 1u);
    return (ushort)((u + rounding) >> 16);
}

// ---------------- W[K][128] fp32 -> Wt[128][K] bf16 ----------------
__global__ void wtrans_k(const float* __restrict__ W, ushort* __restrict__ Wt, int K) {
    int i = blockIdx.x * 256 + threadIdx.x;
    if (i < K * 128) {
        int k = i >> 7, n = i & 127;
        Wt[(size_t)n * K + k] = f2bf(W[i]);
    }
}

// ---------------- MFMA GEMM: H[M x 128](bf16) = A[M x K] * Wt^T ----------------
template<int K, bool AF32>
__global__ __launch_bounds__(256) void mfma_gemm_k(const void* __restrict__ Ap,
                                                   const ushort* __restrict__ Bt, // [128][K] bf16
                                                   ushort* __restrict__ H,        // [M][128] bf16
                                                   int M) {
    int tid = threadIdx.x;
    int w   = tid >> 6;
    int l   = tid & 63;
    int row = blockIdx.x * 64 + w * 16 + (l & 15);
    int rc  = row < M ? row : M - 1;
    int kg  = (l >> 4) * 8;

    const ushort* A16 = (const ushort*)Ap;
    const float*  A32 = (const float*)Ap;

    f32x4 acc[8];
#pragma unroll
    for (int c = 0; c < 8; ++c) acc[c] = (f32x4){0.f, 0.f, 0.f, 0.f};

#pragma unroll
    for (int k0 = 0; k0 < K; k0 += 32) {
        short8 a;
        if (AF32) {
            const float* ap = &A32[(size_t)rc * K + k0 + kg];
            float4 f0 = *(const float4*)ap;
            float4 f1 = *(const float4*)(ap + 4);
            a[0] = (short)f2bf(f0.x); a[1] = (short)f2bf(f0.y);
            a[2] = (short)f2bf(f0.z); a[3] = (short)f2bf(f0.w);
            a[4] = (short)f2bf(f1.x); a[5] = (short)f2bf(f1.y);
            a[6] = (short)f2bf(f1.z); a[7] = (short)f2bf(f1.w);
        } else {
            a = *(const short8*)&A16[(size_t)rc * K + k0 + kg];
        }
#pragma unroll
        for (int c = 0; c < 8; ++c) {
            short8 b = *(const short8*)&Bt[(size_t)(c * 16 + (l & 15)) * K + k0 + kg];
            acc[c] = __builtin_amdgcn_mfma_f32_16x16x32_bf16(a, b, acc[c], 0, 0, 0);
        }
    }

    int r_base = blockIdx.x * 64 + w * 16 + (l >> 4) * 4;
    int colb   = l & 15;
#pragma unroll
    for (int c = 0; c < 8; ++c) {
#pragma unroll
        for (int j = 0; j < 4; ++j) {
            int r = r_base + j;
            if (r < M) H[(size_t)r * 128 + c * 16 + colb] = f2bf(acc[c][j]);
        }
    }
}

// ---------------- aggregate: relu(dis[n]*sum_e(ew*hb[src]) + hb[n]*dinv[n] + b) ----------------
template<bool LAST>
__global__ __launch_bounds__(256) void aggregate_k(const ushort* __restrict__ hb,
                                                   const int* __restrict__ row_ptr,
                                                   const int* __restrict__ col,
                                                   const float* __restrict__ ew,
                                                   const float* __restrict__ dis,
                                                   const float* __restrict__ dinv,
                                                   const float* __restrict__ bias,
                                                   ushort* __restrict__ act,
                                                   float* __restrict__ out, int n) {
    int node = blockIdx.x * 4 + (threadIdx.x >> 6);
    if (node >= n) return;
    int lane = threadIdx.x & 63;
    const char* base = (const char*)hb + (lane << 2);   // lane*4 bytes, row stride 256B

    float ax = 0.f, ay = 0.f;
    int beg = row_ptr[node], end = row_ptr[node + 1];
    for (int e = beg; e < end; e += 8) {
        int   s[8]; float wv[8];
#pragma unroll
        for (int q = 0; q < 8; ++q) {
            int idx = e + q;
            bool v  = idx < end;
            int ic  = v ? idx : (end - 1);
            s[q]  = col[ic];
            wv[q] = v ? ew[ic] : 0.f;
        }
        uint u[8];
#pragma unroll
        for (int q = 0; q < 8; ++q)
            u[q] = *(const uint*)(base + ((size_t)s[q] << 8));
#pragma unroll
        for (int q = 0; q < 8; ++q) {
            ax += wv[q] * __uint_as_float(u[q] << 16);
            ay += wv[q] * __uint_as_float(u[q] & 0xffff0000u);
        }
    }
    float dn = dis[node], di = dinv[node];
    uint un = *(const uint*)(base + ((size_t)node << 8));
    float hx = __uint_as_float(un << 16);
    float hy = __uint_as_float(un & 0xffff0000u);
    int c0 = lane * 2;
    float2 bv = *(const float2*)&bias[c0];
    float ox = fmaxf(ax * dn + hx * di + bv.x, 0.f);
    float oy = fmaxf(ay * dn + hy * di + bv.y, 0.f);
    if (LAST) {
        *(float2*)&out[(size_t)node * D_HID + c0] = make_float2(ox, oy);
    } else {
        uint p = (uint)f2bf(ox) | ((uint)f2bf(oy) << 16);
        *(uint*)((char*)act + ((size_t)node << 8) + (lane << 2)) = p;
    }
}

extern "C" void kernel_launch(void* const* d_in, const int* in_sizes, int n_in,
                              void* d_out, int out_size, void* d_ws, size_t ws_size,
                              hipStream_t stream) {
    const float* x  = (const float*)d_in[0];
    const int*   ei = (const int*)d_in[1];
    const float* W0 = (const float*)d_in[2];
    const float* b0 = (const float*)d_in[3];
    const float* W1 = (const float*)d_in[4];
    const float* b1 = (const float*)d_in[5];
    const float* W2 = (const float*)d_in[6];
    const float* b2 = (const float*)d_in[7];
    float* out = (float*)d_out;

    const int N = N_NODES, E = N_EDGES;
    const int* src = ei;
    const int* dst = ei + E;

    char* w = (char*)d_ws;
    size_t off = 0;
    auto alloc = [&](size_t bytes) {
        size_t o = off;
        off += (bytes + 255) & ~(size_t)255;
        return o;
    };
    int*    cnt    = (int*)(w + alloc((size_t)N * 4));
    int*    cursor = (int*)(w + alloc((size_t)N * 4));
    float*  dis    = (float*)(w + alloc((size_t)N * 4));
    float*  dinv   = (float*)(w + alloc((size_t)N * 4));
    int*    rp     = (int*)(w + alloc((size_t)(N + 1) * 4));
    int*    bsum   = (int*)(w + alloc((size_t)SCAN_NB * 4));
    int*    boff   = (int*)(w + alloc((size_t)SCAN_NB * 4));
    int*    col    = (int*)(w + alloc((size_t)E * 4));
    float*  ewt    = (float*)(w + alloc((size_t)E * 4));
    ushort* hb     = (ushort*)(w + alloc((size_t)N * D_HID * 2));
    ushort* act    = (ushort*)(w + alloc((size_t)N * D_HID * 2));
    ushort* Wt0    = (ushort*)(w + alloc((size_t)128 * 256 * 2));
    ushort* Wt1    = (ushort*)(w + alloc((size_t)128 * 128 * 2));
    ushort* Wt2    = (ushort*)(w + alloc((size_t)128 * 128 * 2));
    (void)ws_size; (void)n_in; (void)in_sizes; (void)out_size;

    hipMemsetAsync(cnt, 0, (size_t)N * 4, stream);
    hipMemsetAsync(cursor, 0, (size_t)N * 4, stream);

    deg_count_k<<<(E + 255) / 256, 256, 0, stream>>>(dst, cnt, E);
    deg_norm_k<<<(N + 255) / 256, 256, 0, stream>>>(cnt, dis, dinv, N);
    bsum_k<<<SCAN_NB, 256, 0, stream>>>(cnt, bsum, N);
    bscan_k<<<1, 256, 0, stream>>>(bsum, boff, rp + N, SCAN_NB);
    scan3_k<<<SCAN_NB, 256, 0, stream>>>(cnt, boff, rp, N);
    scatter_k<<<(E + 255) / 256, 256, 0, stream>>>(src, dst, rp, cursor, col, ewt, dis, E);

    wtrans_k<<<(256 * 128 + 255) / 256, 256, 0, stream>>>(W0, Wt0, 256);
    wtrans_k<<<(128 * 128 + 255) / 256, 256, 0, stream>>>(W1, Wt1, 128);
    wtrans_k<<<(128 * 128 + 255) / 256, 256, 0, stream>>>(W2, Wt2, 128);

    int gemm_grid = (N + 63) / 64;
    int agg_grid  = (N + 3) / 4;

    // layer 0
    mfma_gemm_k<256, true><<<gemm_grid, 256, 0, stream>>>(x, Wt0, hb, N);
    aggregate_k<false><<<agg_grid, 256, 0, stream>>>(hb, rp, col, ewt, dis, dinv, b0, act, out, N);
    // layer 1
    mfma_gemm_k<128, false><<<gemm_grid, 256, 0, stream>>>(act, Wt1, hb, N);
    aggregate_k<false><<<agg_grid, 256, 0, stream>>>(hb, rp, col, ewt, dis, dinv, b1, act, out, N);
    // layer 2
    mfma_gemm_k<128, false><<<gemm_grid, 256, 0, stream>>>(act, Wt2, hb, N);
    aggregate_k<true><<<agg_grid, 256, 0, stream>>>(hb, rp, col, ewt, dis, dinv, b2, act, out, N);
}